// Round 1
// 542.965 us; speedup vs baseline: 1.0432x; 1.0432x over previous
//
#include <hip/hip_runtime.h>
#include <hip/hip_bf16.h>
#include <stdint.h>

#define BDIM 4
#define SDIM 1024
#define DDIM 1024
#define HDIM 16
#define DHDIM 64

typedef __bf16 bf16_t;
typedef __bf16 bf16x8 __attribute__((ext_vector_type(8)));
typedef __bf16 bf16x4 __attribute__((ext_vector_type(4)));
typedef float f32x4 __attribute__((ext_vector_type(4)));

typedef __attribute__((address_space(3))) uint32_t lds_u32;
typedef const __attribute__((address_space(1))) uint32_t glb_u32;

__device__ __forceinline__ void glds16(const void* g, void* l) {
    __builtin_amdgcn_global_load_lds((glb_u32*)g, (lds_u32*)l, 16, 0, 0);
}

// ---------------- conversions ----------------

__global__ __launch_bounds__(256) void convert_x_kernel(const float* __restrict__ X,
                                                        bf16_t* __restrict__ Xb, int n) {
    int i = (blockIdx.x * 256 + threadIdx.x) * 4;
    if (i >= n) return;
    float4 v = *(const float4*)(X + i);
    bf16x4 o;
    o[0] = (bf16_t)v.x; o[1] = (bf16_t)v.y; o[2] = (bf16_t)v.z; o[3] = (bf16_t)v.w;
    *(bf16x4*)(Xb + i) = o;
}

// W[k][n] fp32 -> Wt[n][k] bf16, for 4 weights (z selects)
__global__ __launch_bounds__(256) void transpose_w_kernel(const float* __restrict__ W0,
                                                          const float* __restrict__ W1,
                                                          const float* __restrict__ W2,
                                                          const float* __restrict__ W3,
                                                          bf16_t* __restrict__ Wt) {
    __shared__ float tile[32][33];
    int z = blockIdx.z;
    const float* W = (z == 0) ? W0 : (z == 1) ? W1 : (z == 2) ? W2 : W3;
    bf16_t* dst = Wt + (size_t)z * DDIM * DDIM;
    int bx = blockIdx.x * 32;  // n tile
    int by = blockIdx.y * 32;  // k tile
    int x = threadIdx.x & 31, y0 = threadIdx.x >> 5;
#pragma unroll
    for (int i = 0; i < 4; i++) {
        int y = y0 + i * 8;
        tile[y][x] = W[(size_t)(by + y) * DDIM + bx + x];
    }
    __syncthreads();
#pragma unroll
    for (int i = 0; i < 4; i++) {
        int y = y0 + i * 8;
        dst[(size_t)(bx + y) * DDIM + by + x] = (bf16_t)tile[x][y];
    }
}

// Detect mask element layout: uint8 bools -> bytes at i%4!=0 nonzero somewhere;
// int32 -> those bytes all 0. flag=1 means stride 1 (uint8), else stride 4.
__global__ __launch_bounds__(1024) void mask_flag_kernel(const unsigned char* __restrict__ mb,
                                                         int* __restrict__ flag) {
    __shared__ int any;
    if (threadIdx.x == 0) any = 0;
    __syncthreads();
    int loc = 0;
    for (int i = threadIdx.x; i < BDIM * SDIM; i += 1024)
        if ((i & 3) && mb[i]) loc = 1;
    if (loc) any = 1;
    __syncthreads();
    if (threadIdx.x == 0) *flag = any ? 1 : 0;
}

// ---------------- GEMM: C[m,n] = sum_k A[m,k] * Bt[n,k] (m97-style) ----------------
// MODE 0: write Q bf16 [B,H,S,DH] (scaled 0.125), K bf16 [B,H,S,DH], V TRANSPOSED
//         as Vt [B,H,DH,S]. N=3072.
// MODE 1: write fp32 C row-major [M,1024]
template <int MODE>
__global__ __launch_bounds__(256) void gemm_bt_kernel(const bf16_t* __restrict__ A,
                                                      const bf16_t* __restrict__ Bt,
                                                      bf16_t* __restrict__ Qo, bf16_t* __restrict__ Ko,
                                                      bf16_t* __restrict__ Vto, float* __restrict__ Co) {
    __shared__ bf16_t As[128 * 32];
    __shared__ bf16_t Bs[128 * 32];
    const int m0 = blockIdx.x * 128;
    const int n0 = blockIdx.y * 128;
    const int t = threadIdx.x;
    const int lane = t & 63, w = t >> 6;
    const int wm = w & 1, wn = w >> 1;
    const int low = lane & 15, quad = lane >> 4;
    f32x4 acc[4][4] = {};

    // global_load_lds: wave w stages rows [w*16, w*16+16); lds dest = base + lane*16B
    const int srow = w * 16 + (lane >> 2);
    const int koff = (lane & 3) * 8;
    const bf16_t* Ag = A + (size_t)(m0 + srow) * DDIM + koff;
    const bf16_t* Bg = Bt + (size_t)(n0 + srow) * DDIM + koff;
    bf16_t* AsW = As + w * 512;
    bf16_t* BsW = Bs + w * 512;

    for (int k0 = 0; k0 < DDIM; k0 += 32) {
        __syncthreads();
        glds16(Ag + k0, AsW);
        glds16(Ag + (size_t)64 * DDIM + k0, AsW + 64 * 32);
        glds16(Bg + k0, BsW);
        glds16(Bg + (size_t)64 * DDIM + k0, BsW + 64 * 32);
        __syncthreads();
        bf16x8 af[4], bv[4];
#pragma unroll
        for (int mt = 0; mt < 4; mt++)
            af[mt] = *(const bf16x8*)(As + (wm * 64 + mt * 16 + low) * 32 + quad * 8);
#pragma unroll
        for (int nt = 0; nt < 4; nt++)
            bv[nt] = *(const bf16x8*)(Bs + (wn * 64 + nt * 16 + low) * 32 + quad * 8);
#pragma unroll
        for (int mt = 0; mt < 4; mt++)
#pragma unroll
            for (int nt = 0; nt < 4; nt++)
                acc[mt][nt] = __builtin_amdgcn_mfma_f32_16x16x32_bf16(af[mt], bv[nt], acc[mt][nt], 0, 0, 0);
    }

#pragma unroll
    for (int mt = 0; mt < 4; mt++) {
        const int mbase = m0 + wm * 64 + mt * 16 + quad * 4;
#pragma unroll
        for (int nt = 0; nt < 4; nt++) {
            const int ncol = n0 + wn * 64 + nt * 16 + low;
            if (MODE == 0) {
                const int which = ncol >> 10, nl = ncol & 1023;
                const int hh = nl >> 6, dh = nl & 63;
                const int bb = mbase >> 10, s = mbase & 1023;
                if (which == 2) {
                    // V transposed: Vt[b,h][dh][s]; r -> 4 consecutive s -> one 8B store
                    bf16x4 pv;
#pragma unroll
                    for (int r = 0; r < 4; r++) pv[r] = (bf16_t)acc[mt][nt][r];
                    *(bf16x4*)(Vto + ((size_t)((bb * HDIM + hh) * DHDIM + dh)) * SDIM + s) = pv;
                } else if (which == 0) {
#pragma unroll
                    for (int r = 0; r < 4; r++)
                        Qo[((size_t)(bb * HDIM + hh) * SDIM + (s + r)) * DHDIM + dh] =
                            (bf16_t)(acc[mt][nt][r] * 0.125f);
                } else {
#pragma unroll
                    for (int r = 0; r < 4; r++)
                        Ko[((size_t)(bb * HDIM + hh) * SDIM + (s + r)) * DHDIM + dh] =
                            (bf16_t)acc[mt][nt][r];
                }
            } else {
#pragma unroll
                for (int r = 0; r < 4; r++)
                    Co[(size_t)(mbase + r) * DDIM + ncol] = acc[mt][nt][r];
            }
        }
    }
}

// ---------------- fused attention, 16 heads per block, 1 head per wave --------
// grid: (S/16, B); block 1024 = 16 waves; wave w = head w, q rows [q0, q0+16).
// SWAPPED QK^T: sacc = mfma(Kfrag, Qfrag) -> C[row=k][col=q], so each lane owns
// one q row (q = q0+low) and 8 of the 32 chunk keys (its quad's share).
// Softmax: 7 in-lane fmax + 2 shfl_xor (quads) for max; same for sum. P is
// k-contiguous per lane -> 2x ds_write_b64. Bias staged [h][q][k+pad] with one
// ds_write_b128 per thread (thread owns 8 consecutive k at fixed (q,h)).
// K fragments register-prefetched one chunk ahead; Vt issued at chunk top.
__global__ __launch_bounds__(1024, 4) void attn_kernel(const bf16_t* __restrict__ Q,
                                                       const bf16_t* __restrict__ K,
                                                       const bf16_t* __restrict__ Vt,
                                                       const float* __restrict__ inter,
                                                       const unsigned char* __restrict__ maskb,
                                                       const int* __restrict__ flagp,
                                                       bf16_t* __restrict__ hid) {
    constexpr int KS = 40;            // k stride (32 k + 8 pad) in bf16
    constexpr int HS = 16 * KS + 8;   // head stride = 648 bf16 (dword stride 324 == 4 mod 32)
    __shared__ bf16_t bias_l[2][16 * HS];  // 2 x 20736 B
    __shared__ bf16_t P[16][16 * KS];      // per-wave P tiles (16q x 32k, pad 8), 20 KB
    const int b = blockIdx.y;
    const int q0 = blockIdx.x * 16;
    const int t = threadIdx.x;
    const int w = t >> 6, lane = t & 63;
    const int low = lane & 15, quad = lane >> 4;
    const int h = w;
    const int mstride = (*flagp) ? 1 : 4;

    // ---- staging role: wave w stages bias q-row (q0+w); lane -> (h, k0) ----
    const int sh = lane & 15;          // h of this thread's 8 floats
    const int sk0 = (lane >> 4) * 8;   // k base (8 consecutive k per thread)
    const float* srcB = inter + ((size_t)(b * SDIM + q0 + w) * SDIM + sk0) * HDIM + sh;
    const unsigned char* mb = maskb + (size_t)b * SDIM * mstride;
    const int stoff = sh * HS + w * KS + sk0;  // LDS write offset (16B aligned)

    // Q fragments (B-operand; col = low -> q = q0+low) for head h
    const bf16_t* Qb = Q + ((size_t)(b * HDIM + h) * SDIM + q0) * DHDIM;
    bf16x8 qf0 = *(const bf16x8*)(Qb + low * DHDIM + quad * 8);
    bf16x8 qf1 = *(const bf16x8*)(Qb + low * DHDIM + 32 + quad * 8);

    const bf16_t* Kb = K + (size_t)(b * HDIM + h) * SDIM * DHDIM;
    const bf16_t* VtB = Vt + (size_t)(b * HDIM + h) * DHDIM * SDIM;
    bf16_t* Pw = &P[w][0];

    float mrow = -3.0e38f, lrow = 0.f;
    f32x4 accO[4] = {};

    // ---- prologue: K frags chunk 0 + bias chunk 0 staged into buf 0 ----
    bf16x8 kA0 = *(const bf16x8*)(Kb + (size_t)(0 + low) * DHDIM + quad * 8);
    bf16x8 kA1 = *(const bf16x8*)(Kb + (size_t)(0 + low) * DHDIM + 32 + quad * 8);
    bf16x8 kB0 = *(const bf16x8*)(Kb + (size_t)(16 + low) * DHDIM + quad * 8);
    bf16x8 kB1 = *(const bf16x8*)(Kb + (size_t)(16 + low) * DHDIM + 32 + quad * 8);
    {
        float b0v[8], pen0[8];
#pragma unroll
        for (int j = 0; j < 8; j++) b0v[j] = srcB[j * HDIM];
        if (mstride == 1) {
            uint64_t mw = *(const uint64_t*)(mb + sk0);
#pragma unroll
            for (int j = 0; j < 8; j++) pen0[j] = ((mw >> (8 * j)) & 0xff) ? 0.f : 1.0e9f;
        } else {
            const int4* mp = (const int4*)(mb + (size_t)sk0 * 4);
            int4 ma = mp[0], mc = mp[1];
            pen0[0] = ma.x ? 0.f : 1.0e9f; pen0[1] = ma.y ? 0.f : 1.0e9f;
            pen0[2] = ma.z ? 0.f : 1.0e9f; pen0[3] = ma.w ? 0.f : 1.0e9f;
            pen0[4] = mc.x ? 0.f : 1.0e9f; pen0[5] = mc.y ? 0.f : 1.0e9f;
            pen0[6] = mc.z ? 0.f : 1.0e9f; pen0[7] = mc.w ? 0.f : 1.0e9f;
        }
        bf16x8 bw;
#pragma unroll
        for (int j = 0; j < 8; j++) bw[j] = (bf16_t)(b0v[j] - pen0[j]);
        *(bf16x8*)(&bias_l[0][stoff]) = bw;
    }

    for (int c = 0; c < SDIM / 32; c++) {
        __syncthreads();  // bias tile c visible; prior readers of buf[(c+1)&1] done
        const int kbase = c * 32;

        // ---- issue V^T loads for the current chunk (consumed ~at PV) ----
        bf16x8 vf[4];
#pragma unroll
        for (int nt = 0; nt < 4; nt++)
            vf[nt] = *(const bf16x8*)(VtB + (size_t)(nt * 16 + low) * SDIM + kbase + quad * 8);

        // ---- issue next-chunk prefetch (K frags + bias + mask) ----
        bf16x8 nA0, nA1, nB0, nB1;
        float nb[8], npen[8];
        if (c < SDIM / 32 - 1) {
            const int k2 = kbase + 32;
            const bf16_t* kpA = Kb + (size_t)(k2 + low) * DHDIM;
            const bf16_t* kpB = Kb + (size_t)(k2 + 16 + low) * DHDIM;
            nA0 = *(const bf16x8*)(kpA + quad * 8);
            nA1 = *(const bf16x8*)(kpA + 32 + quad * 8);
            nB0 = *(const bf16x8*)(kpB + quad * 8);
            nB1 = *(const bf16x8*)(kpB + 32 + quad * 8);
            const float* s2 = srcB + (size_t)(c + 1) * 512;
#pragma unroll
            for (int j = 0; j < 8; j++) nb[j] = s2[j * HDIM];
            const int kb2 = k2 + sk0;
            if (mstride == 1) {
                uint64_t mw = *(const uint64_t*)(mb + kb2);
#pragma unroll
                for (int j = 0; j < 8; j++) npen[j] = ((mw >> (8 * j)) & 0xff) ? 0.f : 1.0e9f;
            } else {
                const int4* mp = (const int4*)(mb + (size_t)kb2 * 4);
                int4 ma = mp[0], mc = mp[1];
                npen[0] = ma.x ? 0.f : 1.0e9f; npen[1] = ma.y ? 0.f : 1.0e9f;
                npen[2] = ma.z ? 0.f : 1.0e9f; npen[3] = ma.w ? 0.f : 1.0e9f;
                npen[4] = mc.x ? 0.f : 1.0e9f; npen[5] = mc.y ? 0.f : 1.0e9f;
                npen[6] = mc.z ? 0.f : 1.0e9f; npen[7] = mc.w ? 0.f : 1.0e9f;
            }
        }

        // ---- S^T = K Q^T for 32 keys (swapped: row=k, col=q) ----
        f32x4 s0 = {}, s1 = {};
        s0 = __builtin_amdgcn_mfma_f32_16x16x32_bf16(kA0, qf0, s0, 0, 0, 0);
        s0 = __builtin_amdgcn_mfma_f32_16x16x32_bf16(kA1, qf1, s0, 0, 0, 0);
        s1 = __builtin_amdgcn_mfma_f32_16x16x32_bf16(kB0, qf0, s1, 0, 0, 0);
        s1 = __builtin_amdgcn_mfma_f32_16x16x32_bf16(kB1, qf1, s1, 0, 0, 0);

        // ---- + bias (mask folded): lane q = low, k = nt*16 + quad*4 + r ----
        const bf16_t* bc = &bias_l[c & 1][h * HS + low * KS];
        bf16x4 bv0 = *(const bf16x4*)(bc + quad * 4);
        bf16x4 bv1 = *(const bf16x4*)(bc + 16 + quad * 4);
        float sv[8];
#pragma unroll
        for (int r = 0; r < 4; r++) {
            sv[r] = s0[r] + (float)bv0[r];
            sv[4 + r] = s1[r] + (float)bv1[r];
        }

        // ---- online softmax: lane owns q-row, 8 keys; cross-quad via 2 shfl ----
        float vmx = sv[0];
#pragma unroll
        for (int j = 1; j < 8; j++) vmx = fmaxf(vmx, sv[j]);
        vmx = fmaxf(vmx, __shfl_xor(vmx, 16));
        vmx = fmaxf(vmx, __shfl_xor(vmx, 32));
        float mn = fmaxf(mrow, vmx);
        float alpha = __expf(mrow - mn);
        mrow = mn;
        float ps = 0.f;
        bf16x4 p0, p1;
#pragma unroll
        for (int j = 0; j < 4; j++) {
            float e0 = __expf(sv[j] - mn);
            float e1 = __expf(sv[4 + j] - mn);
            ps += e0 + e1;
            p0[j] = (bf16_t)e0;
            p1[j] = (bf16_t)e1;
        }
        ps += __shfl_xor(ps, 16);
        ps += __shfl_xor(ps, 32);
        lrow = lrow * alpha + ps;

        // ---- rescale accO (rows q = quad*4+r; alpha lives at lane low=q) ----
#pragma unroll
        for (int r = 0; r < 4; r++) {
            float ar = __shfl(alpha, (lane & 48) | (quad * 4 + r));
#pragma unroll
            for (int nt = 0; nt < 4; nt++) accO[nt][r] *= ar;
        }

        // ---- P -> wave-private LDS (A layout rows q=low), 2x b64, no barrier ----
        *(bf16x4*)(Pw + low * KS + quad * 4) = p0;
        *(bf16x4*)(Pw + low * KS + 16 + quad * 4) = p1;
        bf16x8 pf = *(const bf16x8*)(Pw + low * KS + quad * 8);

        // ---- O += P V (K=32 contraction; V^T B-frags from global) ----
#pragma unroll
        for (int nt = 0; nt < 4; nt++)
            accO[nt] = __builtin_amdgcn_mfma_f32_16x16x32_bf16(pf, vf[nt], accO[nt], 0, 0, 0);

        // ---- stage chunk c+1 into the other buffer; rotate K frags ----
        if (c < SDIM / 32 - 1) {
            bf16x8 bw;
#pragma unroll
            for (int j = 0; j < 8; j++) bw[j] = (bf16_t)(nb[j] - npen[j]);
            *(bf16x8*)(&bias_l[(c + 1) & 1][stoff]) = bw;
            kA0 = nA0; kA1 = nA1; kB0 = nB0; kB1 = nB1;
        }
    }

    // epilogue: hidden[b, q, h*64+dh] bf16; 1/l gathered from lane low=q
    float linv = 1.f / lrow;
#pragma unroll
    for (int r = 0; r < 4; r++) {
        float lr = __shfl(linv, (lane & 48) | (quad * 4 + r));
#pragma unroll
        for (int nt = 0; nt < 4; nt++) {
            hid[((size_t)b * SDIM + q0 + quad * 4 + r) * DDIM + h * 64 + nt * 16 + low] =
                (bf16_t)(accO[nt][r] * lr);
        }
    }
}

// ---------------- launcher ----------------

extern "C" void kernel_launch(void* const* d_in, const int* in_sizes, int n_in,
                              void* d_out, int out_size, void* d_ws, size_t ws_size,
                              hipStream_t stream) {
    const float* X = (const float*)d_in[0];
    const unsigned char* maskb = (const unsigned char*)d_in[1];
    const float* inter = (const float*)d_in[2];
    const float* WQ = (const float*)d_in[3];
    const float* WK = (const float*)d_in[4];
    const float* WV = (const float*)d_in[5];
    const float* WO = (const float*)d_in[6];
    float* out = (float*)d_out;

    char* ws = (char*)d_ws;
    const size_t MB = 1024 * 1024;
    bf16_t* Xb  = (bf16_t*)(ws + 0 * MB);
    bf16_t* Wt  = (bf16_t*)(ws + 8 * MB);    // [4][1024][1024] bf16 transposed
    bf16_t* Qm  = (bf16_t*)(ws + 16 * MB);   // [B,H,S,DH]
    bf16_t* Km  = (bf16_t*)(ws + 24 * MB);   // [B,H,S,DH]
    bf16_t* Vtm = (bf16_t*)(ws + 32 * MB);   // [B,H,DH,S]  (transposed V)
    bf16_t* hid = (bf16_t*)(ws + 40 * MB);   // [B,S,D] bf16
    int* flag   = (int*)(ws + 48 * MB);

    convert_x_kernel<<<BDIM * SDIM * DDIM / (256 * 4), 256, 0, stream>>>(X, Xb, BDIM * SDIM * DDIM);
    transpose_w_kernel<<<dim3(32, 32, 4), 256, 0, stream>>>(WQ, WK, WV, WO, Wt);
    mask_flag_kernel<<<1, 1024, 0, stream>>>(maskb, flag);
    // QKV projection: M=4096, N=3072 (Wt_Q|Wt_K|Wt_V contiguous)
    gemm_bt_kernel<0><<<dim3(32, 24), 256, 0, stream>>>(Xb, Wt, Qm, Km, Vtm, nullptr);
    // fused attention reading interaction bias directly
    attn_kernel<<<dim3(SDIM / 16, BDIM), 1024, 0, stream>>>(Qm, Km, Vtm, inter, maskb, flag, hid);
    // output projection: M=4096, N=1024
    gemm_bt_kernel<1><<<dim3(32, 8), 256, 0, stream>>>(hid, Wt + (size_t)3 * DDIM * DDIM,
                                                       nullptr, nullptr, nullptr, out);
}

// Round 2
// 529.782 us; speedup vs baseline: 1.0692x; 1.0249x over previous
//
#include <hip/hip_runtime.h>
#include <hip/hip_bf16.h>
#include <stdint.h>

#define BDIM 4
#define SDIM 1024
#define DDIM 1024
#define HDIM 16
#define DHDIM 64

typedef __bf16 bf16_t;
typedef __bf16 bf16x8 __attribute__((ext_vector_type(8)));
typedef __bf16 bf16x4 __attribute__((ext_vector_type(4)));
typedef float f32x4 __attribute__((ext_vector_type(4)));

typedef __attribute__((address_space(3))) uint32_t lds_u32;
typedef const __attribute__((address_space(1))) uint32_t glb_u32;

__device__ __forceinline__ void glds16(const void* g, void* l) {
    __builtin_amdgcn_global_load_lds((glb_u32*)g, (lds_u32*)l, 16, 0, 0);
}

// ---------------- conversions ----------------

__global__ __launch_bounds__(256) void convert_x_kernel(const float* __restrict__ X,
                                                        bf16_t* __restrict__ Xb, int n) {
    int i = (blockIdx.x * 256 + threadIdx.x) * 4;
    if (i >= n) return;
    float4 v = *(const float4*)(X + i);
    bf16x4 o;
    o[0] = (bf16_t)v.x; o[1] = (bf16_t)v.y; o[2] = (bf16_t)v.z; o[3] = (bf16_t)v.w;
    *(bf16x4*)(Xb + i) = o;
}

// W[k][n] fp32 -> Wt[n][k] bf16, for 4 weights (z selects)
__global__ __launch_bounds__(256) void transpose_w_kernel(const float* __restrict__ W0,
                                                          const float* __restrict__ W1,
                                                          const float* __restrict__ W2,
                                                          const float* __restrict__ W3,
                                                          bf16_t* __restrict__ Wt) {
    __shared__ float tile[32][33];
    int z = blockIdx.z;
    const float* W = (z == 0) ? W0 : (z == 1) ? W1 : (z == 2) ? W2 : W3;
    bf16_t* dst = Wt + (size_t)z * DDIM * DDIM;
    int bx = blockIdx.x * 32;  // n tile
    int by = blockIdx.y * 32;  // k tile
    int x = threadIdx.x & 31, y0 = threadIdx.x >> 5;
#pragma unroll
    for (int i = 0; i < 4; i++) {
        int y = y0 + i * 8;
        tile[y][x] = W[(size_t)(by + y) * DDIM + bx + x];
    }
    __syncthreads();
#pragma unroll
    for (int i = 0; i < 4; i++) {
        int y = y0 + i * 8;
        dst[(size_t)(bx + y) * DDIM + by + x] = (bf16_t)tile[x][y];
    }
}

// Detect mask element layout: uint8 bools -> bytes at i%4!=0 nonzero somewhere;
// int32 -> those bytes all 0. flag=1 means stride 1 (uint8), else stride 4.
__global__ __launch_bounds__(1024) void mask_flag_kernel(const unsigned char* __restrict__ mb,
                                                         int* __restrict__ flag) {
    __shared__ int any;
    if (threadIdx.x == 0) any = 0;
    __syncthreads();
    int loc = 0;
    for (int i = threadIdx.x; i < BDIM * SDIM; i += 1024)
        if ((i & 3) && mb[i]) loc = 1;
    if (loc) any = 1;
    __syncthreads();
    if (threadIdx.x == 0) *flag = any ? 1 : 0;
}

// ---------------- GEMM: C[m,n] = sum_k A[m,k] * Bt[n,k] (m97-style) ----------------
template <int MODE>
__global__ __launch_bounds__(256) void gemm_bt_kernel(const bf16_t* __restrict__ A,
                                                      const bf16_t* __restrict__ Bt,
                                                      bf16_t* __restrict__ Qo, bf16_t* __restrict__ Ko,
                                                      bf16_t* __restrict__ Vto, float* __restrict__ Co) {
    __shared__ bf16_t As[128 * 32];
    __shared__ bf16_t Bs[128 * 32];
    const int m0 = blockIdx.x * 128;
    const int n0 = blockIdx.y * 128;
    const int t = threadIdx.x;
    const int lane = t & 63, w = t >> 6;
    const int wm = w & 1, wn = w >> 1;
    const int low = lane & 15, quad = lane >> 4;
    f32x4 acc[4][4] = {};

    const int srow = w * 16 + (lane >> 2);
    const int koff = (lane & 3) * 8;
    const bf16_t* Ag = A + (size_t)(m0 + srow) * DDIM + koff;
    const bf16_t* Bg = Bt + (size_t)(n0 + srow) * DDIM + koff;
    bf16_t* AsW = As + w * 512;
    bf16_t* BsW = Bs + w * 512;

    for (int k0 = 0; k0 < DDIM; k0 += 32) {
        __syncthreads();
        glds16(Ag + k0, AsW);
        glds16(Ag + (size_t)64 * DDIM + k0, AsW + 64 * 32);
        glds16(Bg + k0, BsW);
        glds16(Bg + (size_t)64 * DDIM + k0, BsW + 64 * 32);
        __syncthreads();
        bf16x8 af[4], bv[4];
#pragma unroll
        for (int mt = 0; mt < 4; mt++)
            af[mt] = *(const bf16x8*)(As + (wm * 64 + mt * 16 + low) * 32 + quad * 8);
#pragma unroll
        for (int nt = 0; nt < 4; nt++)
            bv[nt] = *(const bf16x8*)(Bs + (wn * 64 + nt * 16 + low) * 32 + quad * 8);
#pragma unroll
        for (int mt = 0; mt < 4; mt++)
#pragma unroll
            for (int nt = 0; nt < 4; nt++)
                acc[mt][nt] = __builtin_amdgcn_mfma_f32_16x16x32_bf16(af[mt], bv[nt], acc[mt][nt], 0, 0, 0);
    }

#pragma unroll
    for (int mt = 0; mt < 4; mt++) {
        const int mbase = m0 + wm * 64 + mt * 16 + quad * 4;
#pragma unroll
        for (int nt = 0; nt < 4; nt++) {
            const int ncol = n0 + wn * 64 + nt * 16 + low;
            if (MODE == 0) {
                const int which = ncol >> 10, nl = ncol & 1023;
                const int hh = nl >> 6, dh = nl & 63;
                const int bb = mbase >> 10, s = mbase & 1023;
                if (which == 2) {
                    bf16x4 pv;
#pragma unroll
                    for (int r = 0; r < 4; r++) pv[r] = (bf16_t)acc[mt][nt][r];
                    *(bf16x4*)(Vto + ((size_t)((bb * HDIM + hh) * DHDIM + dh)) * SDIM + s) = pv;
                } else if (which == 0) {
#pragma unroll
                    for (int r = 0; r < 4; r++)
                        Qo[((size_t)(bb * HDIM + hh) * SDIM + (s + r)) * DHDIM + dh] =
                            (bf16_t)(acc[mt][nt][r] * 0.125f);
                } else {
#pragma unroll
                    for (int r = 0; r < 4; r++)
                        Ko[((size_t)(bb * HDIM + hh) * SDIM + (s + r)) * DHDIM + dh] =
                            (bf16_t)acc[mt][nt][r];
                }
            } else {
#pragma unroll
                for (int r = 0; r < 4; r++)
                    Co[(size_t)(mbase + r) * DDIM + ncol] = acc[mt][nt][r];
            }
        }
    }
}

// ---------------- fused attention ----------------
// 256 blocks x 512 threads (8 waves). Decode blockIdx so XCD (bid&7) determines
// (batch b = xcd>>1, head-half hh = xcd&1): each XCD's 32 blocks share ONE
// 2 MB K/V slice (fits 4 MB L2; re-touched every chunk by all 32 CUs -> L2-hot).
// Wave w = head hh*8+w, processes TWO q-tiles (q0, q0+16) sharing the same
// in-register K/V chunk fragments -> K/V traffic halved vs 1 tile/wave.
// 2 blocks/CU (LDS ~52 KB, VGPR <= 128) -> independent barrier domains overlap.
// Swapped QK^T (mfma(K,Q)): lane owns q=low, k=quad*4+r(+16nt).
// Bias: fp32 global -> bf16 LDS [tile][h][q][k] with mask folded, double-buffered,
// register-prefetched one chunk ahead (one float4 per lane per q-row).
__global__ __launch_bounds__(512, 4) void attn_kernel(const bf16_t* __restrict__ Q,
                                                      const bf16_t* __restrict__ K,
                                                      const bf16_t* __restrict__ Vt,
                                                      const float* __restrict__ inter,
                                                      const unsigned char* __restrict__ maskb,
                                                      const int* __restrict__ flagp,
                                                      bf16_t* __restrict__ hid) {
    constexpr int KS = 40;             // k stride (32 k + 8 pad) bf16
    constexpr int HS = 16 * KS + 8;    // per (tile,h) stride = 648 bf16
    constexpr int BUFE = 2 * 8 * HS;   // per buffer: 10368 bf16
    __shared__ bf16_t bias_l[2][BUFE];  // 41.5 KB
    __shared__ bf16_t P[8][16 * KS];    // 10.25 KB
    const int bid = blockIdx.x;
    const int xcd = bid & 7;
    const int b = xcd >> 1, hh = xcd & 1, qi = bid >> 3;
    const int q0 = qi * 32;
    const int t = threadIdx.x;
    const int w = t >> 6, lane = t & 63;
    const int low = lane & 15, quad = lane >> 4;
    const int h = hh * 8 + w;
    const int mstride = (*flagp) ? 1 : 4;

    // staging: wave w stages q-rows {w, w+8, w+16, w+24}; lane -> (k=lane>>1, hp=lane&1)
    const int sk = lane >> 1, shp = lane & 1;
    const float* srcB = inter + ((size_t)(b * SDIM + q0) * SDIM + sk) * HDIM + hh * 8 + shp * 4;
    const unsigned char* mb = maskb + (size_t)b * SDIM * mstride;
    constexpr size_t ROWSTRIDE = (size_t)SDIM * HDIM;  // per +1 q row (dwords)

    // Q fragments: tile A rows q0+low, tile B rows q0+16+low
    const bf16_t* Qb = Q + ((size_t)(b * HDIM + h) * SDIM + q0) * DHDIM;
    bf16x8 qa0 = *(const bf16x8*)(Qb + low * DHDIM + quad * 8);
    bf16x8 qa1 = *(const bf16x8*)(Qb + low * DHDIM + 32 + quad * 8);
    bf16x8 qb0 = *(const bf16x8*)(Qb + (16 + low) * DHDIM + quad * 8);
    bf16x8 qb1 = *(const bf16x8*)(Qb + (16 + low) * DHDIM + 32 + quad * 8);

    const bf16_t* Kb = K + (size_t)(b * HDIM + h) * SDIM * DHDIM;
    const bf16_t* VtB = Vt + (size_t)(b * HDIM + h) * DHDIM * SDIM;
    bf16_t* Pw = &P[w][0];

    float mA = -3.0e38f, lA = 0.f, mB = -3.0e38f, lB = 0.f;
    f32x4 accA[4] = {}, accB[4] = {};

    // ---- prologue: stage bias chunk 0 into buf 0 ----
    {
        float4 v[4];
#pragma unroll
        for (int i = 0; i < 4; i++)
            v[i] = *(const float4*)(srcB + (size_t)(w + i * 8) * ROWSTRIDE);
        float pen = mb[sk * mstride] ? 0.f : 1.0e9f;
#pragma unroll
        for (int i = 0; i < 4; i++) {
            const int r4 = w + i * 8;
            bf16_t* d = &bias_l[0][(size_t)(r4 >> 4) * (8 * HS) + (shp * 4) * HS + (r4 & 15) * KS + sk];
            d[0 * HS] = (bf16_t)(v[i].x - pen);
            d[1 * HS] = (bf16_t)(v[i].y - pen);
            d[2 * HS] = (bf16_t)(v[i].z - pen);
            d[3 * HS] = (bf16_t)(v[i].w - pen);
        }
    }

    for (int c = 0; c < SDIM / 32; c++) {
        __syncthreads();  // bias buf[c&1] visible; previous readers of buf[(c+1)&1] done
        const int kbase = c * 32;

        // ---- prefetch next-chunk bias + mask (lands during compute) ----
        float4 nv[4]; float npen = 0.f;
        if (c < SDIM / 32 - 1) {
#pragma unroll
            for (int i = 0; i < 4; i++)
                nv[i] = *(const float4*)(srcB + (size_t)(w + i * 8) * ROWSTRIDE + (size_t)(c + 1) * 32 * HDIM);
            npen = mb[((c + 1) * 32 + sk) * mstride] ? 0.f : 1.0e9f;
        }

        // ---- K chunk fragments (shared by both q-tiles) ----
        const bf16_t* kpA = Kb + (size_t)(kbase + low) * DHDIM;
        const bf16_t* kpB = Kb + (size_t)(kbase + 16 + low) * DHDIM;
        bf16x8 kA0 = *(const bf16x8*)(kpA + quad * 8);
        bf16x8 kA1 = *(const bf16x8*)(kpA + 32 + quad * 8);
        bf16x8 kB0 = *(const bf16x8*)(kpB + quad * 8);
        bf16x8 kB1 = *(const bf16x8*)(kpB + 32 + quad * 8);

        // ---- S^T = K Q^T for both tiles (row=k, col=q) ----
        f32x4 sA0 = {}, sA1 = {}, sB0 = {}, sB1 = {};
        sA0 = __builtin_amdgcn_mfma_f32_16x16x32_bf16(kA0, qa0, sA0, 0, 0, 0);
        sA0 = __builtin_amdgcn_mfma_f32_16x16x32_bf16(kA1, qa1, sA0, 0, 0, 0);
        sA1 = __builtin_amdgcn_mfma_f32_16x16x32_bf16(kB0, qa0, sA1, 0, 0, 0);
        sA1 = __builtin_amdgcn_mfma_f32_16x16x32_bf16(kB1, qa1, sA1, 0, 0, 0);
        sB0 = __builtin_amdgcn_mfma_f32_16x16x32_bf16(kA0, qb0, sB0, 0, 0, 0);
        sB0 = __builtin_amdgcn_mfma_f32_16x16x32_bf16(kA1, qb1, sB0, 0, 0, 0);
        sB1 = __builtin_amdgcn_mfma_f32_16x16x32_bf16(kB0, qb0, sB1, 0, 0, 0);
        sB1 = __builtin_amdgcn_mfma_f32_16x16x32_bf16(kB1, qb1, sB1, 0, 0, 0);

        // ---- V^T fragments (shared by both tiles) ----
        bf16x8 vf[4];
#pragma unroll
        for (int nt = 0; nt < 4; nt++)
            vf[nt] = *(const bf16x8*)(VtB + (size_t)(nt * 16 + low) * SDIM + kbase + quad * 8);

        // ================= tile A =================
        {
            const bf16_t* bc = &bias_l[c & 1][(size_t)0 * (8 * HS) + w * HS + low * KS];
            bf16x4 bv0 = *(const bf16x4*)(bc + quad * 4);
            bf16x4 bv1 = *(const bf16x4*)(bc + 16 + quad * 4);
            float sv[8];
#pragma unroll
            for (int r = 0; r < 4; r++) {
                sv[r] = sA0[r] + (float)bv0[r];
                sv[4 + r] = sA1[r] + (float)bv1[r];
            }
            float vmx = sv[0];
#pragma unroll
            for (int j = 1; j < 8; j++) vmx = fmaxf(vmx, sv[j]);
            vmx = fmaxf(vmx, __shfl_xor(vmx, 16));
            vmx = fmaxf(vmx, __shfl_xor(vmx, 32));
            float mn = fmaxf(mA, vmx);
            float alpha = __expf(mA - mn);
            mA = mn;
            float ps = 0.f;
            bf16x4 p0, p1;
#pragma unroll
            for (int j = 0; j < 4; j++) {
                float e0 = __expf(sv[j] - mn);
                float e1 = __expf(sv[4 + j] - mn);
                ps += e0 + e1;
                p0[j] = (bf16_t)e0;
                p1[j] = (bf16_t)e1;
            }
            ps += __shfl_xor(ps, 16);
            ps += __shfl_xor(ps, 32);
            lA = lA * alpha + ps;
#pragma unroll
            for (int r = 0; r < 4; r++) {
                float ar = __shfl(alpha, (lane & 48) | (quad * 4 + r));
#pragma unroll
                for (int nt = 0; nt < 4; nt++) accA[nt][r] *= ar;
            }
            *(bf16x4*)(Pw + low * KS + quad * 4) = p0;
            *(bf16x4*)(Pw + low * KS + 16 + quad * 4) = p1;
            bf16x8 pf = *(const bf16x8*)(Pw + low * KS + quad * 8);
#pragma unroll
            for (int nt = 0; nt < 4; nt++)
                accA[nt] = __builtin_amdgcn_mfma_f32_16x16x32_bf16(pf, vf[nt], accA[nt], 0, 0, 0);
        }

        // ================= tile B =================
        {
            const bf16_t* bc = &bias_l[c & 1][(size_t)1 * (8 * HS) + w * HS + low * KS];
            bf16x4 bv0 = *(const bf16x4*)(bc + quad * 4);
            bf16x4 bv1 = *(const bf16x4*)(bc + 16 + quad * 4);
            float sv[8];
#pragma unroll
            for (int r = 0; r < 4; r++) {
                sv[r] = sB0[r] + (float)bv0[r];
                sv[4 + r] = sB1[r] + (float)bv1[r];
            }
            float vmx = sv[0];
#pragma unroll
            for (int j = 1; j < 8; j++) vmx = fmaxf(vmx, sv[j]);
            vmx = fmaxf(vmx, __shfl_xor(vmx, 16));
            vmx = fmaxf(vmx, __shfl_xor(vmx, 32));
            float mn = fmaxf(mB, vmx);
            float alpha = __expf(mB - mn);
            mB = mn;
            float ps = 0.f;
            bf16x4 p0, p1;
#pragma unroll
            for (int j = 0; j < 4; j++) {
                float e0 = __expf(sv[j] - mn);
                float e1 = __expf(sv[4 + j] - mn);
                ps += e0 + e1;
                p0[j] = (bf16_t)e0;
                p1[j] = (bf16_t)e1;
            }
            ps += __shfl_xor(ps, 16);
            ps += __shfl_xor(ps, 32);
            lB = lB * alpha + ps;
#pragma unroll
            for (int r = 0; r < 4; r++) {
                float ar = __shfl(alpha, (lane & 48) | (quad * 4 + r));
#pragma unroll
                for (int nt = 0; nt < 4; nt++) accB[nt][r] *= ar;
            }
            *(bf16x4*)(Pw + low * KS + quad * 4) = p0;
            *(bf16x4*)(Pw + low * KS + 16 + quad * 4) = p1;
            bf16x8 pf = *(const bf16x8*)(Pw + low * KS + quad * 8);
#pragma unroll
            for (int nt = 0; nt < 4; nt++)
                accB[nt] = __builtin_amdgcn_mfma_f32_16x16x32_bf16(pf, vf[nt], accB[nt], 0, 0, 0);
        }

        // ---- stage chunk c+1 into the other buffer ----
        if (c < SDIM / 32 - 1) {
#pragma unroll
            for (int i = 0; i < 4; i++) {
                const int r4 = w + i * 8;
                bf16_t* d = &bias_l[(c + 1) & 1]
                                   [(size_t)(r4 >> 4) * (8 * HS) + (shp * 4) * HS + (r4 & 15) * KS + sk];
                d[0 * HS] = (bf16_t)(nv[i].x - npen);
                d[1 * HS] = (bf16_t)(nv[i].y - npen);
                d[2 * HS] = (bf16_t)(nv[i].z - npen);
                d[3 * HS] = (bf16_t)(nv[i].w - npen);
            }
        }
    }

    // ---- epilogue: hidden[b, q, h*64+dh] bf16 for both tiles ----
    float liA = 1.f / lA, liB = 1.f / lB;
#pragma unroll
    for (int r = 0; r < 4; r++) {
        float lrA = __shfl(liA, (lane & 48) | (quad * 4 + r));
        float lrB = __shfl(liB, (lane & 48) | (quad * 4 + r));
#pragma unroll
        for (int nt = 0; nt < 4; nt++) {
            hid[((size_t)b * SDIM + q0 + quad * 4 + r) * DDIM + h * 64 + nt * 16 + low] =
                (bf16_t)(accA[nt][r] * lrA);
            hid[((size_t)b * SDIM + q0 + 16 + quad * 4 + r) * DDIM + h * 64 + nt * 16 + low] =
                (bf16_t)(accB[nt][r] * lrB);
        }
    }
}

// ---------------- launcher ----------------

extern "C" void kernel_launch(void* const* d_in, const int* in_sizes, int n_in,
                              void* d_out, int out_size, void* d_ws, size_t ws_size,
                              hipStream_t stream) {
    const float* X = (const float*)d_in[0];
    const unsigned char* maskb = (const unsigned char*)d_in[1];
    const float* inter = (const float*)d_in[2];
    const float* WQ = (const float*)d_in[3];
    const float* WK = (const float*)d_in[4];
    const float* WV = (const float*)d_in[5];
    const float* WO = (const float*)d_in[6];
    float* out = (float*)d_out;

    char* ws = (char*)d_ws;
    const size_t MB = 1024 * 1024;
    bf16_t* Xb  = (bf16_t*)(ws + 0 * MB);
    bf16_t* Wt  = (bf16_t*)(ws + 8 * MB);    // [4][1024][1024] bf16 transposed
    bf16_t* Qm  = (bf16_t*)(ws + 16 * MB);   // [B,H,S,DH]
    bf16_t* Km  = (bf16_t*)(ws + 24 * MB);   // [B,H,S,DH]
    bf16_t* Vtm = (bf16_t*)(ws + 32 * MB);   // [B,H,DH,S]  (transposed V)
    bf16_t* hid = (bf16_t*)(ws + 40 * MB);   // [B,S,D] bf16
    int* flag   = (int*)(ws + 48 * MB);

    convert_x_kernel<<<BDIM * SDIM * DDIM / (256 * 4), 256, 0, stream>>>(X, Xb, BDIM * SDIM * DDIM);
    transpose_w_kernel<<<dim3(32, 32, 4), 256, 0, stream>>>(WQ, WK, WV, WO, Wt);
    mask_flag_kernel<<<1, 1024, 0, stream>>>(maskb, flag);
    gemm_bt_kernel<0><<<dim3(32, 24), 256, 0, stream>>>(Xb, Wt, Qm, Km, Vtm, nullptr);
    attn_kernel<<<dim3(256), 512, 0, stream>>>(Qm, Km, Vtm, inter, maskb, flag, hid);
    gemm_bt_kernel<1><<<dim3(32, 8), 256, 0, stream>>>(hid, Wt + (size_t)3 * DDIM * DDIM,
                                                       nullptr, nullptr, nullptr, out);
}